// Round 6
// baseline (208.049 us; speedup 1.0000x reference)
//
#include <hip/hip_runtime.h>
#include <hip/hip_bf16.h>

#define N_TOT  8192
#define B_HALF 4096
#define D_DIM  256
#define PARTW  8      /* column groups (1024 cols each) */
#define MFIX   192.0f /* fixed softmax shift, log2 domain */

typedef short bf16x8 __attribute__((ext_vector_type(8)));
typedef float f32x4  __attribute__((ext_vector_type(4)));

#define NEG_INF (-__builtin_inff())
#define RSCALE  1.6986436f     /* sqrt(2*log2e): scaled dot = logits in log2 units */
#define LN2F    0.69314718056f

__device__ __forceinline__ float exp2_fast(float x) {
  float r;
  asm("v_exp_f32 %0, %1" : "=v"(r) : "v"(x));
  return r;
}

__device__ __forceinline__ unsigned short f2b(float f) {
  __hip_bfloat16 h = __float2bfloat16(f);
  return *reinterpret_cast<unsigned short*>(&h);
}

__global__ __launch_bounds__(256) void convert_k(const float* __restrict__ zis,
                                                 const float* __restrict__ zjs,
                                                 unsigned short* __restrict__ reps,
                                                 float* __restrict__ out,
                                                 int* __restrict__ counter) {
  size_t idx = ((size_t)blockIdx.x * 256 + threadIdx.x) * 4;
  const float* src = (idx < (size_t)B_HALF * D_DIM) ? (zjs + idx)
                                                    : (zis + (idx - (size_t)B_HALF * D_DIM));
  float4 v = *reinterpret_cast<const float4*>(src);
  ushort4 o;
  o.x = f2b(v.x * RSCALE); o.y = f2b(v.y * RSCALE);
  o.z = f2b(v.z * RSCALE); o.w = f2b(v.w * RSCALE);
  *reinterpret_cast<ushort4*>(reps + idx) = o;
  if (blockIdx.x == 0 && threadIdx.x < 2) out[threadIdx.x] = 0.0f;
  if (blockIdx.x == 0 && threadIdx.x == 2) *counter = 0;
}

#define G2L(srcp, ldsp)                                                          \
  __builtin_amdgcn_global_load_lds(                                              \
      (const __attribute__((address_space(1))) void*)(srcp),                     \
      (__attribute__((address_space(3))) void*)(ldsp), 16, 0, 0)

// Long-pipeline fused GEMM+softmax. Grid 256 (1 block/CU): 256-row panel x
// 1024-col group, 16 phase-iters (4 col-tiles x 4 K-tiles) x 4 phases.
__global__ __launch_bounds__(512, 2) void ntxent_main(const unsigned short* __restrict__ reps,
                                                      float* __restrict__ part_m,
                                                      float* __restrict__ part_s,
                                                      float* __restrict__ pos_out,
                                                      int* __restrict__ counter,
                                                      float* __restrict__ out) {
  __shared__ short As[32768];   // 2 slots x [256 rows x 64 k] 32KB
  __shared__ short Bs[32768];

  const int tid  = threadIdx.x;
  const int lane = tid & 63;
  const int l15  = lane & 15;
  const int l4   = lane >> 4;
  const int wave = tid >> 6;
  const int wr   = wave >> 2;   // 2 row-halves of 128
  const int wc   = wave & 3;    // 4 col-quarters of 64

  // XCD-aware mapping: XCD x gets row-panels (x&3)*8.. and col-halves (x>>2)
  const int xcd  = (int)blockIdx.x & 7;
  const int idx  = (int)blockIdx.x >> 3;        // 0..31
  const int rp   = (xcd & 3) * 8 + (idx >> 2);  // 0..31 row panel
  const int cg   = (xcd >> 2) * 4 + (idx & 3);  // 0..7 col group
  const int R0   = rp * 256;
  const int G0   = cg * 1024;
  const bool dblk = (cg == (rp >> 2));
  const bool pblk = (cg == (((rp >> 2) + 4) & 7));
  const int  sct  = rp & 3;                      // special col-tile

#define ISSUE_A(hh, sbase, ko)                                                      \
  do {                                                                              \
    _Pragma("unroll") for (int j_ = 0; j_ < 2; ++j_) {                              \
      const int u_ = tid >> 3;                                                      \
      const unsigned short* s_ = reps + (size_t)(R0 + j_ * 128 + (hh) * 64 + u_) * D_DIM \
                                 + (ko) + (((tid & 7) ^ (u_ & 7)) * 8);             \
      G2L(s_, (sbase) + (((hh) * 2 + j_) * 512 + tid) * 8);                         \
    }                                                                               \
  } while (0)

#define ISSUE_B(gg, sbase, cb, ko)                                                  \
  do {                                                                              \
    _Pragma("unroll") for (int j_ = 0; j_ < 2; ++j_) {                              \
      const int u_ = tid >> 3;                                                      \
      const int col_ = (cb) + (u_ & 31) + (gg) * 32 + (((j_ * 2) + (u_ >> 5)) & 3) * 64; \
      const unsigned short* s_ = reps + (size_t)col_ * D_DIM                        \
                                 + (ko) + (((tid & 7) ^ (u_ & 7)) * 8);             \
      G2L(s_, (sbase) + (((gg) * 2 + j_) * 512 + tid) * 8);                         \
    }                                                                               \
  } while (0)

#define READ_A(hh, sbase)                                                           \
  do {                                                                              \
    _Pragma("unroll") for (int mf = 0; mf < 4; ++mf)                                \
      _Pragma("unroll") for (int kk = 0; kk < 2; ++kk)                              \
        af[mf][kk] = *reinterpret_cast<const bf16x8*>(                              \
            (sbase) + ((hh) * 128 + wr * 64 + mf * 16 + l15) * 64 +                 \
            (((kk * 4 + l4) ^ (l15 & 7)) * 8));                                     \
  } while (0)

#define READ_B(gg, dst, sbase)                                                      \
  do {                                                                              \
    _Pragma("unroll") for (int nf = 0; nf < 2; ++nf)                                \
      _Pragma("unroll") for (int kk = 0; kk < 2; ++kk)                              \
        dst[nf][kk] = *reinterpret_cast<const bf16x8*>(                             \
            (sbase) + ((gg) * 128 + wc * 32 + nf * 16 + l15) * 64 +                 \
            (((kk * 4 + l4) ^ (l15 & 7)) * 8));                                     \
  } while (0)

#define MFMA_Q(h, g, bfx)                                                           \
  do {                                                                              \
    _Pragma("unroll") for (int mf = 0; mf < 4; ++mf)                                \
      _Pragma("unroll") for (int nf = 0; nf < 2; ++nf)                              \
        _Pragma("unroll") for (int kk = 0; kk < 2; ++kk)                            \
          acc[h][g][mf][nf] = __builtin_amdgcn_mfma_f32_16x16x32_bf16(              \
              af[mf][kk], bfx[nf][kk], acc[h][g][mf][nf], 0, 0, 0);                 \
  } while (0)

  // streamed quadrant epilogue at kt==3: exp2-accumulate + zero acc
#define EPI(h, g)                                                                   \
  do {                                                                              \
    _Pragma("unroll") for (int mf = 0; mf < 4; ++mf)                                \
      _Pragma("unroll") for (int nf = 0; nf < 2; ++nf)                              \
        _Pragma("unroll") for (int r = 0; r < 4; ++r) {                             \
          float v = acc[h][g][mf][nf][r];                                           \
          if (spec) {                                                               \
            const bool own = ((8 * wr + 4 * (h) + mf) == (4 * wc + 2 * (g) + nf))   \
                             && (l15 == l4 * 4 + r);                                \
            if (own) {                                                              \
              if (doD) v = NEG_INF;                                                 \
              else pos_out[R0 + wr * 128 + (h) * 64 + mf * 16 + l15] = v;           \
            }                                                                       \
          }                                                                         \
          m_st[h][mf][r] = fmaxf(m_st[h][mf][r], v);                                \
          s_st[h][mf][r] += exp2_fast(v - MFIX);                                    \
          acc[h][g][mf][nf][r] = 0.f;                                               \
        }                                                                           \
  } while (0)

#define PHASE_MID()                                          \
  do {                                                       \
    __builtin_amdgcn_s_barrier();                            \
    asm volatile("s_waitcnt lgkmcnt(0)" ::: "memory");       \
    __builtin_amdgcn_sched_barrier(0);                       \
    __builtin_amdgcn_s_setprio(1);                           \
  } while (0)

  f32x4 acc[2][2][4][2];
  const f32x4 vz = {0.f, 0.f, 0.f, 0.f};
  float m_st[2][4][4], s_st[2][4][4];
#pragma unroll
  for (int h = 0; h < 2; ++h)
#pragma unroll
    for (int mf = 0; mf < 4; ++mf) {
#pragma unroll
      for (int r = 0; r < 4; ++r) { m_st[h][mf][r] = NEG_INF; s_st[h][mf][r] = 0.f; }
#pragma unroll
      for (int g = 0; g < 2; ++g)
#pragma unroll
        for (int nf = 0; nf < 2; ++nf) acc[h][g][mf][nf] = vz;
    }

  bf16x8 af[4][2], bf0[2][2], bf1[2][2];

  // prologue: iter-0 tiles into slot 0, consumption order A0,B0,B1,A1
  ISSUE_A(0, As, 0); ISSUE_B(0, Bs, G0, 0); ISSUE_B(1, Bs, G0, 0); ISSUE_A(1, As, 0);
  asm volatile("s_waitcnt vmcnt(4)" ::: "memory");
  __builtin_amdgcn_s_barrier();

  for (int it = 0; it < 15; ++it) {
    const int ct = it >> 2;
    const bool kt3 = (it & 3) == 3;
    short* Ac = As + ((it & 1) << 14);
    short* Bc = Bs + ((it & 1) << 14);
    short* An = As + (((it & 1) ^ 1) << 14);
    short* Bn = Bs + (((it & 1) ^ 1) << 14);
    const int nko = ((it + 1) & 3) << 6;          // next K offset (shorts)
    const int ncb = G0 + ((it + 1) >> 2) * 256;   // next col base
    const bool doD = dblk && (ct == sct);
    const bool doP = pblk && (ct == sct);
    const bool spec = doD || doP;

    // P0: quadrant (0,0); stage A0(next)
    READ_A(0, Ac); READ_B(0, bf0, Bc); ISSUE_A(0, An, nko);
    PHASE_MID(); MFMA_Q(0, 0, bf0);
    __builtin_amdgcn_s_setprio(0);
    if (kt3) EPI(0, 0);
    asm volatile("s_waitcnt vmcnt(4)" ::: "memory");
    __builtin_amdgcn_s_barrier();
    // P1: (0,1); stage B0(next)
    READ_B(1, bf1, Bc); ISSUE_B(0, Bn, ncb, nko);
    PHASE_MID(); MFMA_Q(0, 1, bf1);
    __builtin_amdgcn_s_setprio(0);
    if (kt3) EPI(0, 1);
    asm volatile("s_waitcnt vmcnt(4)" ::: "memory");
    __builtin_amdgcn_s_barrier();
    // P2: (1,1); stage B1(next)
    READ_A(1, Ac); ISSUE_B(1, Bn, ncb, nko);
    PHASE_MID(); MFMA_Q(1, 1, bf1);
    __builtin_amdgcn_s_setprio(0);
    if (kt3) EPI(1, 1);
    __builtin_amdgcn_s_barrier();
    // P3: (1,0); re-read bf0 (frees its long lifetime); stage A1(next)
    READ_B(0, bf0, Bc); ISSUE_A(1, An, nko);
    PHASE_MID(); MFMA_Q(1, 0, bf0);
    __builtin_amdgcn_s_setprio(0);
    if (kt3) EPI(1, 0);
    asm volatile("s_waitcnt vmcnt(4)" ::: "memory");
    __builtin_amdgcn_s_barrier();
  }

  // tail it=15 (ct=3, kt=3, slot 1): drain 4 -> 2 -> 0, EPI every phase
  {
    const bool doD = dblk && (3 == sct);
    const bool doP = pblk && (3 == sct);
    const bool spec = doD || doP;
    short* Ac = As + (1 << 14);
    short* Bc = Bs + (1 << 14);
    READ_A(0, Ac); READ_B(0, bf0, Bc);
    PHASE_MID(); MFMA_Q(0, 0, bf0);
    __builtin_amdgcn_s_setprio(0);
    EPI(0, 0);
    asm volatile("s_waitcnt vmcnt(2)" ::: "memory");
    __builtin_amdgcn_s_barrier();
    READ_B(1, bf1, Bc);
    PHASE_MID(); MFMA_Q(0, 1, bf1);
    __builtin_amdgcn_s_setprio(0);
    EPI(0, 1);
    asm volatile("s_waitcnt vmcnt(0)" ::: "memory");
    __builtin_amdgcn_s_barrier();
    READ_A(1, Ac);
    PHASE_MID(); MFMA_Q(1, 1, bf1);
    __builtin_amdgcn_s_setprio(0);
    EPI(1, 1);
    __builtin_amdgcn_s_barrier();
    READ_B(0, bf0, Bc);
    PHASE_MID(); MFMA_Q(1, 0, bf0);
    __builtin_amdgcn_s_setprio(0);
    EPI(1, 0);
  }
  __syncthreads();

  // block-end reduction: merge l15 lanes (same rows, disjoint cols), then wc waves
  float2* red = reinterpret_cast<float2*>(As);   // [256 rows][4 wc] = 8KB
#pragma unroll
  for (int h = 0; h < 2; ++h)
#pragma unroll
    for (int mf = 0; mf < 4; ++mf)
#pragma unroll
      for (int r = 0; r < 4; ++r) {
        float s = s_st[h][mf][r], m = m_st[h][mf][r];
#pragma unroll
        for (int off = 1; off < 16; off <<= 1) {
          s += __shfl_xor(s, off, 16);
          m = fmaxf(m, __shfl_xor(m, off, 16));
        }
        if (l15 == 0)
          red[(wr * 128 + h * 64 + mf * 16 + l4 * 4 + r) * 4 + wc] = make_float2(m, s);
      }
  __syncthreads();
  if (tid < 256) {
    float2 p0 = red[tid * 4 + 0], p1 = red[tid * 4 + 1];
    float2 p2 = red[tid * 4 + 2], p3 = red[tid * 4 + 3];
    const int i = R0 + tid;
    part_m[i * PARTW + cg] = fmaxf(fmaxf(p0.x, p1.x), fmaxf(p2.x, p3.x));
    part_s[i * PARTW + cg] = p0.y + p1.y + p2.y + p3.y;
  }

  // completion protocol: last block finalizes (device-scope)
  __threadfence();
  __syncthreads();
  __shared__ int isLast;
  if (tid == 0) isLast = (atomicAdd(counter, 1) == 255) ? 1 : 0;
  __syncthreads();
  if (isLast) {
    __threadfence();
    float L = 0.f, H = 0.f;
    for (int row = tid; row < N_TOT; row += 512) {
      float m = NEG_INF, ss = 0.f;
#pragma unroll
      for (int c = 0; c < PARTW; ++c) {
        m  = fmaxf(m, part_m[row * PARTW + c]);
        ss += part_s[row * PARTW + c];
      }
      const float pos = pos_out[row];
      L += (MFIX + __log2f(ss) - pos);
      H += (pos >= m) ? 1.0f : 0.0f;
    }
    L *= LN2F;
#pragma unroll
    for (int off = 32; off; off >>= 1) {
      L += __shfl_down(L, off);
      H += __shfl_down(H, off);
    }
    float* redf = reinterpret_cast<float*>(Bs);
    if ((tid & 63) == 0) { redf[wave * 2] = L; redf[wave * 2 + 1] = H; }
    __syncthreads();
    if (tid == 0) {
      float Lt = 0.f, Ht = 0.f;
#pragma unroll
      for (int w = 0; w < 8; ++w) { Lt += redf[w * 2]; Ht += redf[w * 2 + 1]; }
      out[0] = Lt * (1.0f / 8192.0f);
      out[1] = Ht * (1.0f / 8192.0f);
    }
  }
}

extern "C" void kernel_launch(void* const* d_in, const int* in_sizes, int n_in,
                              void* d_out, int out_size, void* d_ws, size_t ws_size,
                              hipStream_t stream) {
  const float* zis = (const float*)d_in[0];
  const float* zjs = (const float*)d_in[1];
  float* out = (float*)d_out;

  char* ws = (char*)d_ws;
  unsigned short* reps = (unsigned short*)ws;                // 4 MB
  float* part_m = (float*)(ws + 4u * 1024u * 1024u);         // 256 KB
  float* part_s = (float*)(ws + 4u * 1024u * 1024u + 256u * 1024u);
  float* pos_a  = (float*)(ws + 4u * 1024u * 1024u + 512u * 1024u);  // 32 KB
  int*   cnt    = (int*)  (ws + 4u * 1024u * 1024u + 576u * 1024u);
  (void)in_sizes; (void)n_in; (void)out_size; (void)ws_size;

  convert_k<<<2048, 256, 0, stream>>>(zis, zjs, reps, out, cnt);
  ntxent_main<<<256, 512, 0, stream>>>(reps, part_m, part_s, pos_a, cnt, out);
}

// Round 8
// 170.036 us; speedup vs baseline: 1.2236x; 1.2236x over previous
//
#include <hip/hip_runtime.h>
#include <hip/hip_bf16.h>

#define N_TOT  8192
#define B_HALF 4096
#define D_DIM  256
#define NSPLIT 16
#define MFIX   192.0f /* fixed softmax shift, log2 domain */

typedef short bf16x8 __attribute__((ext_vector_type(8)));
typedef float f32x4  __attribute__((ext_vector_type(4)));

#define NEG_INF (-__builtin_inff())
#define RSCALE  1.6986436f     /* sqrt(2*log2e): scaled dot = logits in log2 units */
#define LN2F    0.69314718056f

__device__ __forceinline__ float exp2_fast(float x) {
  float r;
  asm("v_exp_f32 %0, %1" : "=v"(r) : "v"(x));
  return r;
}

__device__ __forceinline__ unsigned short f2b(float f) {
  __hip_bfloat16 h = __float2bfloat16(f);
  return *reinterpret_cast<unsigned short*>(&h);
}

// reps = [zjs; zis]*RSCALE bf16; also zero out/counter/s_arr/m_arr (re-poisoned each launch).
__global__ __launch_bounds__(256) void convert_k(const float* __restrict__ zis,
                                                 const float* __restrict__ zjs,
                                                 unsigned short* __restrict__ reps,
                                                 float* __restrict__ out,
                                                 int* __restrict__ counter,
                                                 float* __restrict__ s_arr,
                                                 unsigned* __restrict__ m_arr) {
  size_t idx = ((size_t)blockIdx.x * 256 + threadIdx.x) * 4;
  const float* src = (idx < (size_t)B_HALF * D_DIM) ? (zjs + idx)
                                                    : (zis + (idx - (size_t)B_HALF * D_DIM));
  float4 v = *reinterpret_cast<const float4*>(src);
  ushort4 o;
  o.x = f2b(v.x * RSCALE); o.y = f2b(v.y * RSCALE);
  o.z = f2b(v.z * RSCALE); o.w = f2b(v.w * RSCALE);
  *reinterpret_cast<ushort4*>(reps + idx) = o;
  if (blockIdx.x < 32)       s_arr[blockIdx.x * 256 + threadIdx.x] = 0.0f;
  else if (blockIdx.x < 64)  m_arr[(blockIdx.x - 32) * 256 + threadIdx.x] = 0u;
  if (blockIdx.x == 64 && threadIdx.x < 2) out[threadIdx.x] = 0.0f;
  if (blockIdx.x == 64 && threadIdx.x == 2) *counter = 0;
}

#define G2L(srcp, ldsp)                                                          \
  __builtin_amdgcn_global_load_lds(                                              \
      (const __attribute__((address_space(1))) void*)(srcp),                     \
      (__attribute__((address_space(3))) void*)(ldsp), 16, 0, 0)

// Co-resident fused GEMM+softmax: grid 1024 = 64 row-blocks (128) x 16 col-splits
// (512). 256 thr / 4 waves (2x2), wave tile 64x64. LDS 64KB -> 2 blocks/CU.
__global__ __launch_bounds__(256, 2) void ntxent_main(const unsigned short* __restrict__ reps,
                                                      float* __restrict__ s_arr,
                                                      unsigned* __restrict__ m_arr,
                                                      float* __restrict__ pos_out,
                                                      int* __restrict__ counter,
                                                      float* __restrict__ out) {
  __shared__ short As[2][8192];   // [slot][128 rows x 64 k] 16KB
  __shared__ short Bs[2][8192];   // [slot][128 cols x 64 k] 16KB

  const int tid  = threadIdx.x;
  const int lane = tid & 63;
  const int l15  = lane & 15;
  const int l4   = lane >> 4;
  const int wave = tid >> 6;
  const int wr   = wave >> 1;   // 2 row-halves of 64
  const int wc   = wave & 1;    // 2 col-halves of 64

  // XCD-bijective swizzle (nwg=1024 % 8 == 0)
  const unsigned wg = (blockIdx.x & 7) * 128 + (blockIdx.x >> 3);
  const int rb = wg >> 4, cs = wg & 15;
  const int R0 = rb * 128, C0 = cs * 512;
  const bool dblk = (cs == (rb >> 2));
  const bool pblk = (cs == (((rb >> 2) + 8) & 15));
  const int  sct  = rb & 3;     // col-tile where diag/pos falls

  // stage one 128x64 K-slice (16KB): linear LDS dest, XOR-swz source (rule 21)
#define STAGE_A(slot, kt)                                                        \
  do {                                                                           \
    _Pragma("unroll") for (int j_ = 0; j_ < 4; ++j_) {                           \
      const int cid_ = j_ * 256 + tid;                                           \
      const int row_ = cid_ >> 3, ch_ = cid_ & 7;                                \
      const unsigned short* s_ = reps + (size_t)(R0 + row_) * D_DIM              \
                                 + (kt) * 64 + ((ch_ ^ (row_ & 7)) * 8);         \
      G2L(s_, &As[slot][cid_ * 8]);                                              \
    }                                                                            \
  } while (0)

#define STAGE_B(slot, ct, kt)                                                    \
  do {                                                                           \
    _Pragma("unroll") for (int j_ = 0; j_ < 4; ++j_) {                           \
      const int cid_ = j_ * 256 + tid;                                           \
      const int col_ = cid_ >> 3, ch_ = cid_ & 7;                                \
      const unsigned short* s_ = reps + (size_t)(C0 + (ct) * 128 + col_) * D_DIM \
                                 + (kt) * 64 + ((ch_ ^ (col_ & 7)) * 8);         \
      G2L(s_, &Bs[slot][cid_ * 8]);                                              \
    }                                                                            \
  } while (0)

  f32x4 acc[4][4];
  const f32x4 vz = {0.f, 0.f, 0.f, 0.f};
  float m_st[4][4], s_st[4][4];
#pragma unroll
  for (int mf = 0; mf < 4; ++mf)
#pragma unroll
    for (int r = 0; r < 4; ++r) {
      acc[mf][r] = vz; m_st[mf][r] = NEG_INF; s_st[mf][r] = 0.f;
    }

  STAGE_A(0, 0); STAGE_B(0, 0, 0);

  for (int it = 0; it < 16; ++it) {
    const int ct = it >> 2, kt = it & 3, sl = it & 1;
    __syncthreads();               // slot sl staged (barrier drains vmcnt)
    if (it < 15) { STAGE_A(sl ^ 1, (it + 1) & 3); STAGE_B(sl ^ 1, (it + 1) >> 2, (it + 1) & 3); }

    bf16x8 af[4][2], bfr[4][2];
#pragma unroll
    for (int mf = 0; mf < 4; ++mf) {
      const int row = wr * 64 + mf * 16 + l15;
#pragma unroll
      for (int kk = 0; kk < 2; ++kk)
        af[mf][kk] = *reinterpret_cast<const bf16x8*>(
            &As[sl][row * 64 + (((kk * 4 + l4) ^ (l15 & 7)) * 8)]);
    }
#pragma unroll
    for (int nf = 0; nf < 4; ++nf) {
      const int col = wc * 64 + nf * 16 + l15;
#pragma unroll
      for (int kk = 0; kk < 2; ++kk)
        bfr[nf][kk] = *reinterpret_cast<const bf16x8*>(
            &Bs[sl][col * 64 + (((kk * 4 + l4) ^ (l15 & 7)) * 8)]);
    }
#pragma unroll
    for (int mf = 0; mf < 4; ++mf)
#pragma unroll
      for (int nf = 0; nf < 4; ++nf)
#pragma unroll
        for (int kk = 0; kk < 2; ++kk)
          acc[mf][nf] = __builtin_amdgcn_mfma_f32_16x16x32_bf16(af[mf][kk], bfr[nf][kk],
                                                                acc[mf][nf], 0, 0, 0);

    if (kt == 3) {   // streamed fixed-M epilogue for this 64x64 sub-result
      const bool spd = dblk && (ct == sct) && (wc == wr);
      const bool spp = pblk && (ct == sct) && (wc == wr);
      if (spd | spp) {
#pragma unroll
        for (int mf = 0; mf < 4; ++mf)
#pragma unroll
          for (int r = 0; r < 4; ++r)
            if (l15 == l4 * 4 + r) {
              if (spd) acc[mf][mf][r] = NEG_INF;                      // mask diagonal
              else pos_out[R0 + wr * 64 + mf * 16 + l15] = acc[mf][mf][r];  // capture positive
            }
      }
#pragma unroll
      for (int mf = 0; mf < 4; ++mf)
#pragma unroll
        for (int r = 0; r < 4; ++r) {
          float u0 = acc[mf][0][r], u1 = acc[mf][1][r];
          float u2 = acc[mf][2][r], u3 = acc[mf][3][r];
          m_st[mf][r] = fmaxf(fmaxf(fmaxf(m_st[mf][r], u0), fmaxf(u1, u2)), u3);
          s_st[mf][r] += exp2_fast(u0 - MFIX) + exp2_fast(u1 - MFIX)
                       + exp2_fast(u2 - MFIX) + exp2_fast(u3 - MFIX);
          acc[mf][0][r] = 0.f; acc[mf][1][r] = 0.f;
          acc[mf][2][r] = 0.f; acc[mf][3][r] = 0.f;
        }
    }
  }

  // block reduction: 16-lane (column) merge -> LDS -> per-row atomics
  __syncthreads();
  float2* red = reinterpret_cast<float2*>(&As[0][0]);   // [128 rows][2 wc]
#pragma unroll
  for (int mf = 0; mf < 4; ++mf)
#pragma unroll
    for (int r = 0; r < 4; ++r) {
      float s = s_st[mf][r], m = m_st[mf][r];
#pragma unroll
      for (int off = 1; off < 16; off <<= 1) {
        s += __shfl_xor(s, off, 16);
        m = fmaxf(m, __shfl_xor(m, off, 16));
      }
      if (l15 == 0)
        red[(wr * 64 + mf * 16 + l4 * 4 + r) * 2 + wc] = make_float2(m, s);
    }
  __syncthreads();
  if (tid < 128) {
    float2 a = red[tid * 2 + 0], b = red[tid * 2 + 1];
    atomicAdd(&s_arr[R0 + tid], a.y + b.y);
    atomicMax(&m_arr[R0 + tid], __float_as_uint(fmaxf(a.x, b.x)));  // m > 0 always
  }

  // completion protocol: last block finalizes
  __threadfence();
  __syncthreads();
  __shared__ int isLast;
  if (tid == 0) isLast = (atomicAdd(counter, 1) == 1023) ? 1 : 0;
  __syncthreads();
  if (isLast) {
    __threadfence();
    float L = 0.f, H = 0.f;
    for (int row = tid; row < N_TOT; row += 256) {
      const float ss  = s_arr[row];
      const float m   = __uint_as_float(m_arr[row]);
      const float pos = pos_out[row];
      L += (MFIX + __log2f(ss) - pos);
      H += (pos >= m) ? 1.0f : 0.0f;
    }
    L *= LN2F;
#pragma unroll
    for (int off = 32; off; off >>= 1) {
      L += __shfl_down(L, off);
      H += __shfl_down(H, off);
    }
    float* redf = reinterpret_cast<float*>(&Bs[0][0]);
    if ((tid & 63) == 0) { redf[wave * 2] = L; redf[wave * 2 + 1] = H; }
    __syncthreads();
    if (tid == 0) {
      float Lt = 0.f, Ht = 0.f;
#pragma unroll
      for (int w = 0; w < 4; ++w) { Lt += redf[w * 2]; Ht += redf[w * 2 + 1]; }
      out[0] = Lt * (1.0f / 8192.0f);
      out[1] = Ht * (1.0f / 8192.0f);
    }
  }
}

extern "C" void kernel_launch(void* const* d_in, const int* in_sizes, int n_in,
                              void* d_out, int out_size, void* d_ws, size_t ws_size,
                              hipStream_t stream) {
  const float* zis = (const float*)d_in[0];
  const float* zjs = (const float*)d_in[1];
  float* out = (float*)d_out;

  char* ws = (char*)d_ws;
  unsigned short* reps = (unsigned short*)ws;                        // 4 MB
  float*    s_arr = (float*)   (ws + 4u * 1024u * 1024u);            // 32 KB
  unsigned* m_arr = (unsigned*)(ws + 4u * 1024u * 1024u + 32u * 1024u);
  float*    pos_a = (float*)   (ws + 4u * 1024u * 1024u + 64u * 1024u);
  int*      cnt   = (int*)     (ws + 4u * 1024u * 1024u + 96u * 1024u);
  (void)in_sizes; (void)n_in; (void)out_size; (void)ws_size;

  convert_k<<<2048, 256, 0, stream>>>(zis, zjs, reps, out, cnt, s_arr, m_arr);
  ntxent_main<<<1024, 256, 0, stream>>>(reps, s_arr, m_arr, pos_a, cnt, out);
}